// Round 3
// baseline (263.080 us; speedup 1.0000x reference)
//
#include <hip/hip_runtime.h>
#include <math.h>

#define NPTS 4096
#define KNN  20
#define NOUT 64
#define BLK  256
#define PT   16    // candidates per thread
#define CAP  1024  // LDS candidate-pool capacity

// monotone float->uint map (total order preserved)
__device__ __forceinline__ unsigned ord32(float f) {
    unsigned u = __float_as_uint(f);
    int m = ((int)u) >> 31;
    return u ^ ((unsigned)m | 0x80000000u);
}

// prologue: xx[b][j] = x0^2 + x1^2 + x2^2
__global__ __launch_bounds__(256) void xx_kernel(const float* __restrict__ x,
                                                 float* __restrict__ xx) {
    const int i = blockIdx.x * 256 + threadIdx.x;   // over B*NPTS
    const int b = i >> 12, j = i & (NPTS - 1);
    const float* xb = x + (size_t)b * 3 * NPTS;
    const float a = xb[j], bb = xb[NPTS + j], c = xb[2 * NPTS + j];
    xx[i] = fmaf(a, a, fmaf(bb, bb, c * c));
}

__global__ __launch_bounds__(BLK) void edgeconv_kernel(
    const float* __restrict__ x,      // (B, 3, N)
    const float* __restrict__ xx,     // (B, N) precomputed squares
    const float* __restrict__ Wm,     // (64, 6)
    const float* __restrict__ gamma,
    const float* __restrict__ beta,
    const float* __restrict__ mean,
    const float* __restrict__ var,
    float* __restrict__ out)          // (B, 64, N)
{
    const int bid = blockIdx.x;
    const int b = bid >> 12;          // N = 4096
    const int n = bid & (NPTS - 1);
    const int t = threadIdx.x;
    const int lane = t & 63;
    const int wid  = t >> 6;

    __shared__ unsigned long long S[CAP];
    __shared__ unsigned long long win[KNN];   // fallback path only
    __shared__ float wTf[4];
    __shared__ int scnt;

    const float* xb = x + (size_t)b * 3 * NPTS;
    const float p0 = xb[n];
    const float p1 = xb[NPTS + n];
    const float p2 = xb[2 * NPTS + n];
    const float q0 = 2.f * p0, q1 = 2.f * p1, q2 = 2.f * p2;
    const float xxp = fmaf(p0, p0, fmaf(p1, p1, p2 * p2));

    // ---- phase 1: distances for 16 contiguous candidates (float regs) ----
    float d[PT];
    const int m0 = t * PT;
    float vmax;
    {
        const float4* X0 = (const float4*)(xb + m0);
        const float4* X1 = (const float4*)(xb + NPTS + m0);
        const float4* X2 = (const float4*)(xb + 2 * NPTS + m0);
        const float4* XQ = (const float4*)(xx + (size_t)b * NPTS + m0);
        #pragma unroll
        for (int j4 = 0; j4 < PT / 4; ++j4) {
            float4 a = X0[j4], bb = X1[j4], cc = X2[j4], sq = XQ[j4];
            d[j4*4+0] = (fmaf(q0, a.x, fmaf(q1, bb.x, q2 * cc.x)) - xxp) - sq.x;
            d[j4*4+1] = (fmaf(q0, a.y, fmaf(q1, bb.y, q2 * cc.y)) - xxp) - sq.y;
            d[j4*4+2] = (fmaf(q0, a.z, fmaf(q1, bb.z, q2 * cc.z)) - xxp) - sq.z;
            d[j4*4+3] = (fmaf(q0, a.w, fmaf(q1, bb.w, q2 * cc.w)) - xxp) - sq.w;
        }
        vmax = d[0];
        #pragma unroll
        for (int j = 1; j < PT; ++j) vmax = fmaxf(vmax, d[j]);
    }

    // ---- phase 2a: per-wave bitonic (desc) of 64 lane maxima; lane4 = 5th ----
    {
        float v = vmax;
        #pragma unroll
        for (int k = 2; k <= 64; k <<= 1) {
            #pragma unroll
            for (int j = k >> 1; j > 0; j >>= 1) {
                float o = __shfl_xor(v, j, 64);
                const bool keep_min = ((lane & j) == 0) == ((lane & k) != 0);
                float mn = fminf(v, o), mx = fmaxf(v, o);
                v = keep_min ? mn : mx;
            }
        }
        if (lane == 4) wTf[wid] = v;
    }
    if (t == 0) scnt = 0;
    __syncthreads();

    const float T = fminf(fminf(wTf[0], wTf[1]), fminf(wTf[2], wTf[3]));

    // ---- phase 2b: compact candidates >= T into LDS pool ----
    #pragma unroll
    for (int j = 0; j < PT; ++j) {
        if (d[j] >= T) {
            int pos = atomicAdd(&scnt, 1);
            if (pos < CAP) {
                int idx = m0 + j;
                S[pos] = ((unsigned long long)ord32(d[j]) << 32) |
                         (unsigned)((NPTS - 1) - idx);   // tie -> lower idx wins
            }
        }
    }
    __syncthreads();

    if (wid != 0) return;   // waves 1..3 done; wave 0 owns selection + epilogue

    int cnt = scnt; if (cnt > CAP) cnt = CAP;

    // ---- phase 2c: wave 0 selects exact top-20 ----
    unsigned long long key;
    if (cnt <= 64) {
        key = (lane < cnt) ? S[lane] : 0ull;
        #pragma unroll
        for (int k = 2; k <= 64; k <<= 1) {
            #pragma unroll
            for (int j = k >> 1; j > 0; j >>= 1) {
                unsigned long long o = __shfl_xor(key, j, 64);
                const bool keep_min = ((lane & j) == 0) == ((lane & k) != 0);
                unsigned long long mn = (key < o) ? key : o;
                unsigned long long mx = (key < o) ? o : key;
                key = keep_min ? mn : mx;
            }
        }
        // lanes 0..19 now hold the top-20 keys (desc)
    } else {
        // rare fallback: 20 extraction rounds over the pool
        for (int r = 0; r < KNN; ++r) {
            unsigned long long bk = 0ull; int bp = -1;
            for (int i = lane; i < cnt; i += 64) {
                unsigned long long kk = S[i];
                if (kk > bk) { bk = kk; bp = i; }
            }
            unsigned long long rb = bk;
            #pragma unroll
            for (int s = 32; s > 0; s >>= 1) {
                unsigned long long o = __shfl_xor(rb, s, 64);
                if (o > rb) rb = o;
            }
            if (bk == rb && bp >= 0) S[bp] = 0ull;  // unique keys -> one owner
            if (lane == 0) win[r] = rb;
        }
        key = (lane < KNN) ? win[lane] : 0ull;
    }

    // ---- phase 3 (wave 0): edge linear + BN + LeakyReLU + max over K ----
    const unsigned lowbits = (unsigned)(key & 0xFFFFFFFFull);
    const int o = lane;
    const float iv    = gamma[o] / sqrtf(var[o] + 1e-5f);
    const float bias  = beta[o] - mean[o] * iv;
    const float* Wr = Wm + o * 6;
    const float w0p = Wr[0] * iv, w1p = Wr[1] * iv, w2p = Wr[2] * iv;
    const float w3p = Wr[3] * iv, w4p = Wr[4] * iv, w5p = Wr[5] * iv;
    const float basep = fmaf(w3p, p0, fmaf(w4p, p1, fmaf(w5p, p2, bias)));

    float best = -INFINITY;
    #pragma unroll
    for (int k = 0; k < KNN; ++k) {
        const unsigned lk = (unsigned)__builtin_amdgcn_readlane((int)lowbits, k);
        const int gi = (NPTS - 1) - (int)lk;            // uniform (SGPR) index
        const float f0 = xb[gi];
        const float f1 = xb[NPTS + gi];
        const float f2 = xb[2 * NPTS + gi];
        float y = fmaf(w0p, f0 - p0, fmaf(w1p, f1 - p1, fmaf(w2p, f2 - p2, basep)));
        y = fmaxf(y, 0.2f * y);                          // LeakyReLU (0<slope<1)
        best = fmaxf(best, y);
    }
    out[((size_t)b * NOUT + o) * NPTS + n] = best;
}

extern "C" void kernel_launch(void* const* d_in, const int* in_sizes, int n_in,
                              void* d_out, int out_size, void* d_ws, size_t ws_size,
                              hipStream_t stream) {
    const float* x     = (const float*)d_in[0];
    const float* Wm    = (const float*)d_in[1];
    const float* gamma = (const float*)d_in[2];
    const float* beta  = (const float*)d_in[3];
    const float* mean  = (const float*)d_in[4];
    const float* var   = (const float*)d_in[5];
    float* out = (float*)d_out;
    float* xx  = (float*)d_ws;                 // B*NPTS floats

    const int B = in_sizes[0] / (3 * NPTS);    // 8
    xx_kernel<<<B * NPTS / 256, 256, 0, stream>>>(x, xx);
    edgeconv_kernel<<<B * NPTS, BLK, 0, stream>>>(x, xx, Wm, gamma, beta, mean, var, out);
}

// Round 4
// 147.875 us; speedup vs baseline: 1.7791x; 1.7791x over previous
//
#include <hip/hip_runtime.h>
#include <math.h>

#define NPTS 4096
#define KNN  20
#define NOUT 64
#define QPB  16              // queries (= waves) per block
#define BLKT (QPB * 64)      // 1024 threads
#define POOLCAP 256

// monotone float->uint map (total order preserved)
__device__ __forceinline__ unsigned ord32(float f) {
    unsigned u = __float_as_uint(f);
    int m = ((int)u) >> 31;
    return u ^ ((unsigned)m | 0x80000000u);
}

__global__ __launch_bounds__(BLKT, 4) void edgeconv_kernel(
    const float* __restrict__ x,      // (B, 3, N)
    const float* __restrict__ Wm,     // (64, 6)
    const float* __restrict__ gamma,
    const float* __restrict__ beta,
    const float* __restrict__ mean,
    const float* __restrict__ var,
    float* __restrict__ out)          // (B, 64, N)
{
    const int bid = blockIdx.x;
    const int b   = bid >> 8;                 // 256 blocks per batch
    const int n0  = (bid & 255) * QPB;
    const int t    = threadIdx.x;
    const int lane = t & 63;
    const int w    = t >> 6;

    __shared__ float4 tile[NPTS];                       // 64 KB: x0,x1,x2,xx
    __shared__ unsigned long long pool[QPB * POOLCAP];  // 32 KB per-wave pools
    __shared__ int cnt[QPB];
    __shared__ float outT[NOUT * 17];                   // padded transpose buf

    const float* xb = x + (size_t)b * 3 * NPTS;

    if (lane == 0) cnt[w] = 0;

    // ---- stage batch points into LDS (coalesced, xx computed inline) ----
    #pragma unroll
    for (int k2 = 0; k2 < NPTS / BLKT; ++k2) {          // 4 iters
        const int c = t + k2 * BLKT;
        const float a0 = xb[c];
        const float a1 = xb[NPTS + c];
        const float a2 = xb[2 * NPTS + c];
        const float sq = fmaf(a0, a0, fmaf(a1, a1, a2 * a2));
        tile[c] = make_float4(a0, a1, a2, sq);
    }
    __syncthreads();

    // ---- this wave's query point ----
    const int n = n0 + w;
    const float4 pv = tile[n];                          // broadcast read
    const float p0 = pv.x, p1 = pv.y, p2 = pv.z, xxp = pv.w;
    const float q0 = 2.f * p0, q1 = 2.f * p1, q2 = 2.f * p2;

    // ---- distances: candidate c = j*64 + lane, j = 0..63 (conflict-free) ----
    float d[64];
    float vmax = -INFINITY;
    const float4* tl = tile + lane;
    #pragma unroll
    for (int g = 0; g < 8; ++g) {
        float4 cc[8];
        #pragma unroll
        for (int u = 0; u < 8; ++u) cc[u] = tl[(g * 8 + u) * 64];
        #pragma unroll
        for (int u = 0; u < 8; ++u) {
            const float dd =
                (fmaf(q0, cc[u].x, fmaf(q1, cc[u].y, q2 * cc[u].z)) - xxp) - cc[u].w;
            d[g * 8 + u] = dd;
            vmax = fmaxf(vmax, dd);
        }
    }

    // ---- threshold: bitonic sort (desc) of 64 lane maxima; T = 20th ----
    float T;
    {
        float v = vmax;
        #pragma unroll
        for (int k = 2; k <= 64; k <<= 1) {
            #pragma unroll
            for (int j = k >> 1; j > 0; j >>= 1) {
                const float o = __shfl_xor(v, j, 64);
                const bool keep_min = ((lane & j) == 0) == ((lane & k) != 0);
                v = keep_min ? fminf(v, o) : fmaxf(v, o);
            }
        }
        T = __shfl(v, 19, 64);     // 20th-largest lane-max; admits all top-20
    }

    // ---- compact survivors into this wave's pool ----
    const int invl = (NPTS - 1) - lane;
    #pragma unroll
    for (int j = 0; j < 64; ++j) {
        if (d[j] >= T) {
            const int pos = atomicAdd(&cnt[w], 1);
            if (pos < POOLCAP)
                pool[w * POOLCAP + pos] =
                    ((unsigned long long)ord32(d[j]) << 32) |
                    (unsigned)(invl - j * 64);           // tie -> lower idx wins
        }
    }
    const int c_ = cnt[w];                               // wave-uniform

    // ---- exact top-20 selection (wave-local) ----
    unsigned long long key = 0ull;
    if (c_ <= 64) {
        if (lane < c_) key = pool[w * POOLCAP + lane];
        #pragma unroll
        for (int k = 2; k <= 64; k <<= 1) {
            #pragma unroll
            for (int j = k >> 1; j > 0; j >>= 1) {
                const unsigned long long o = __shfl_xor(key, j, 64);
                const bool keep_min = ((lane & j) == 0) == ((lane & k) != 0);
                const unsigned long long mn = (key < o) ? key : o;
                const unsigned long long mx = (key < o) ? o : key;
                key = keep_min ? mn : mx;
            }
        }
        // lanes 0..19 hold top-20 keys (desc)
    } else {
        const int cc2 = (c_ < POOLCAP) ? c_ : POOLCAP;   // rare fallback
        for (int r = 0; r < KNN; ++r) {
            unsigned long long bk = 0ull; int bp = -1;
            for (int i = lane; i < cc2; i += 64) {
                const unsigned long long kk = pool[w * POOLCAP + i];
                if (kk > bk) { bk = kk; bp = i; }
            }
            unsigned long long rb = bk;
            #pragma unroll
            for (int s = 32; s > 0; s >>= 1) {
                const unsigned long long o = __shfl_xor(rb, s, 64);
                if (o > rb) rb = o;
            }
            if (bk == rb && bp >= 0) pool[w * POOLCAP + bp] = 0ull; // unique keys
            if (lane == r) key = rb;
        }
    }

    // ---- epilogue: per-wave, lane = output channel ----
    const int o = lane;
    const float iv   = gamma[o] / sqrtf(var[o] + 1e-5f);
    const float bias = beta[o] - mean[o] * iv;
    const float* Wr = Wm + o * 6;
    const float w0p = Wr[0] * iv, w1p = Wr[1] * iv, w2p = Wr[2] * iv;
    const float w3p = Wr[3] * iv, w4p = Wr[4] * iv, w5p = Wr[5] * iv;
    const float basep = fmaf(w3p, p0, fmaf(w4p, p1, fmaf(w5p, p2, bias)));

    const unsigned lowb = (unsigned)(key & 0xFFFFFFFFull);
    float best = -INFINITY;
    #pragma unroll
    for (int k = 0; k < KNN; ++k) {
        const unsigned lk = (unsigned)__builtin_amdgcn_readlane((int)lowb, k);
        const int gi = (NPTS - 1) - (int)lk;             // uniform index
        const float4 f = tile[gi];                       // LDS broadcast
        float y = fmaf(w0p, f.x - p0,
                   fmaf(w1p, f.y - p1,
                    fmaf(w2p, f.z - p2, basep)));
        y = fmaxf(y, 0.2f * y);                          // LeakyReLU
        best = fmaxf(best, y);
    }
    outT[o * 17 + w] = best;
    __syncthreads();

    // ---- coalesced output: 64B-per-row stores ----
    if (t < NOUT * 4) {
        const int oo = t >> 2, seg = t & 3;
        const int s4 = seg * 4;
        float4 vv;
        vv.x = outT[oo * 17 + s4 + 0];
        vv.y = outT[oo * 17 + s4 + 1];
        vv.z = outT[oo * 17 + s4 + 2];
        vv.w = outT[oo * 17 + s4 + 3];
        *(float4*)(out + ((size_t)b * NOUT + oo) * NPTS + n0 + s4) = vv;
    }
}

extern "C" void kernel_launch(void* const* d_in, const int* in_sizes, int n_in,
                              void* d_out, int out_size, void* d_ws, size_t ws_size,
                              hipStream_t stream) {
    const float* x     = (const float*)d_in[0];
    const float* Wm    = (const float*)d_in[1];
    const float* gamma = (const float*)d_in[2];
    const float* beta  = (const float*)d_in[3];
    const float* mean  = (const float*)d_in[4];
    const float* var   = (const float*)d_in[5];
    float* out = (float*)d_out;

    const int B = in_sizes[0] / (3 * NPTS);        // 8
    const int nblocks = B * (NPTS / QPB);          // 8 * 256 = 2048
    edgeconv_kernel<<<nblocks, BLKT, 0, stream>>>(x, Wm, gamma, beta, mean, var, out);
}

// Round 5
// 144.793 us; speedup vs baseline: 1.8169x; 1.0213x over previous
//
#include <hip/hip_runtime.h>
#include <math.h>

#define NPTS 4096
#define KNN  20
#define NOUT 64
#define QPB  8               // queries (= waves) per block
#define BLKT (QPB * 64)      // 512 threads
#define PCAP 96              // per-wave survivor pool capacity
#define HALF 2048            // candidates staged in LDS (j < 32)

// monotone float->uint map (total order preserved)
__device__ __forceinline__ unsigned ord32(float f) {
    unsigned u = __float_as_uint(f);
    int m = ((int)u) >> 31;
    return u ^ ((unsigned)m | 0x80000000u);
}

__device__ __forceinline__ int mbcnt64(unsigned long long m) {
    return __builtin_amdgcn_mbcnt_hi((unsigned)(m >> 32),
           __builtin_amdgcn_mbcnt_lo((unsigned)m, 0));
}

// prologue: xq[b][j] = (x0, x1, x2, -(x0^2+x1^2+x2^2))
__global__ __launch_bounds__(256) void pack_kernel(const float* __restrict__ x,
                                                   float4* __restrict__ xq) {
    const int i = blockIdx.x * 256 + threadIdx.x;   // over B*NPTS
    const int b = i >> 12, j = i & (NPTS - 1);
    const float* xb = x + (size_t)b * 3 * NPTS;
    const float a0 = xb[j], a1 = xb[NPTS + j], a2 = xb[2 * NPTS + j];
    xq[i] = make_float4(a0, a1, a2, -fmaf(a0, a0, fmaf(a1, a1, a2 * a2)));
}

__global__ __launch_bounds__(BLKT, 4) void edgeconv_kernel(
    const float4* __restrict__ xq,    // (B, N) packed points
    const float* __restrict__ Wm,     // (64, 6)
    const float* __restrict__ gamma,
    const float* __restrict__ beta,
    const float* __restrict__ mean,
    const float* __restrict__ var,
    float* __restrict__ out)          // (B, 64, N)
{
    const int bid = blockIdx.x;
    const int b   = bid >> 9;                    // 512 blocks per batch
    const int n0  = (bid & 511) * QPB;
    const int t    = threadIdx.x;
    const int lane = t & 63;
    const int w    = t >> 6;

    __shared__ float4 tile[HALF];                       // 32 KB, candidates 0..2047
    __shared__ unsigned long long pool[QPB * PCAP];     // 6 KB, also idxbuf + outT

    const float4* xqb = xq + (size_t)b * NPTS;

    // ---- stage first half of points into LDS ----
    #pragma unroll
    for (int k2 = 0; k2 < HALF / BLKT; ++k2) {          // 4 iters
        const int c = t + k2 * BLKT;
        tile[c] = xqb[c];
    }
    __syncthreads();

    // ---- this wave's query point (uniform -> scalar load) ----
    const int nu = __builtin_amdgcn_readfirstlane(n0 + w);
    const float4 pv = xqb[nu];
    const float q0 = 2.f * pv.x, q1 = 2.f * pv.y, q2 = 2.f * pv.z;

    // ---- distances: candidate c = j*64+lane; j<32 LDS, j>=32 global(L2) ----
    float d[64];
    float vmax = -INFINITY;
    #pragma unroll
    for (int g = 0; g < 4; ++g) {                       // LDS half
        float4 cc[8];
        #pragma unroll
        for (int u = 0; u < 8; ++u) cc[u] = tile[(g * 8 + u) * 64 + lane];
        #pragma unroll
        for (int u = 0; u < 8; ++u) {
            const float e = fmaf(q0, cc[u].x, fmaf(q1, cc[u].y, fmaf(q2, cc[u].z, cc[u].w)));
            d[g * 8 + u] = e;
            vmax = fmaxf(vmax, e);
        }
    }
    #pragma unroll
    for (int g = 4; g < 8; ++g) {                       // global half (L2-hot)
        float4 cc[8];
        #pragma unroll
        for (int u = 0; u < 8; ++u) cc[u] = xqb[(g * 8 + u) * 64 + lane];
        #pragma unroll
        for (int u = 0; u < 8; ++u) {
            const float e = fmaf(q0, cc[u].x, fmaf(q1, cc[u].y, fmaf(q2, cc[u].z, cc[u].w)));
            d[g * 8 + u] = e;
            vmax = fmaxf(vmax, e);
        }
    }

    // ---- threshold: bitonic (desc) of 64 lane maxima; T = 20th largest ----
    float T;
    {
        float v = vmax;
        #pragma unroll
        for (int k = 2; k <= 64; k <<= 1) {
            #pragma unroll
            for (int j = k >> 1; j > 0; j >>= 1) {
                const float o = __shfl_xor(v, j, 64);
                const bool keep_min = ((lane & j) == 0) == ((lane & k) != 0);
                v = keep_min ? fminf(v, o) : fmaxf(v, o);
            }
        }
        T = __shfl(v, 19, 64);
    }

    // ---- compact survivors (ballot-ranked, no atomics) ----
    const int invl = (NPTS - 1) - lane;
    int base = 0;
    #pragma unroll
    for (int j = 0; j < 64; ++j) {
        const bool surv = d[j] >= T;
        const unsigned long long mk = __ballot(surv);
        if (mk) {
            if (surv) {
                const int pos = base + mbcnt64(mk);
                if (pos < PCAP)
                    pool[w * PCAP + pos] =
                        ((unsigned long long)ord32(d[j]) << 32) |
                        (unsigned)(invl - j * 64);       // tie -> lower idx wins
            }
            base += __popcll(mk);
        }
    }
    const int cnt = (base < PCAP) ? base : PCAP;         // cnt >= 20 guaranteed

    // ---- exact top-20 set selection (order irrelevant for max-pool) ----
    unsigned* idxbuf = (unsigned*)(pool + (size_t)w * PCAP);  // reuse own pool
    unsigned long long kk = 0ull;
    if (lane < cnt) kk = pool[w * PCAP + lane];

    if (cnt <= 64) {
        const unsigned key = (unsigned)(kk >> 32);
        unsigned v = key;
        #pragma unroll
        for (int k = 2; k <= 64; k <<= 1) {
            #pragma unroll
            for (int j = k >> 1; j > 0; j >>= 1) {
                const unsigned o = (unsigned)__shfl_xor((int)v, j, 64);
                const bool keep_min = ((lane & j) == 0) == ((lane & k) != 0);
                v = keep_min ? min(v, o) : max(v, o);
            }
        }
        const unsigned K20 = (unsigned)__shfl((int)v, 19, 64);
        const unsigned long long ge = __ballot(key >= K20);  // pad key=0 never >= K20
        if (__popcll(ge) == KNN) {
            if (key >= K20) idxbuf[mbcnt64(ge)] = (unsigned)kk;
        } else {
            // rare tie path: full u64 sort (value desc, index asc)
            unsigned long long key64 = kk;
            #pragma unroll
            for (int k = 2; k <= 64; k <<= 1) {
                #pragma unroll
                for (int j = k >> 1; j > 0; j >>= 1) {
                    const unsigned long long o = __shfl_xor(key64, j, 64);
                    const bool keep_min = ((lane & j) == 0) == ((lane & k) != 0);
                    const unsigned long long mn = (key64 < o) ? key64 : o;
                    const unsigned long long mx = (key64 < o) ? o : key64;
                    key64 = keep_min ? mn : mx;
                }
            }
            if (lane < KNN) idxbuf[lane] = (unsigned)key64;
        }
    } else {
        // rare overflow path: 20 extraction rounds over the pool
        for (int r = 0; r < KNN; ++r) {
            unsigned long long bk = 0ull; int bp = -1;
            for (int i = lane; i < cnt; i += 64) {
                const unsigned long long e = pool[w * PCAP + i];
                if (e > bk) { bk = e; bp = i; }
            }
            unsigned long long rb = bk;
            #pragma unroll
            for (int s = 32; s > 0; s >>= 1) {
                const unsigned long long o = __shfl_xor(rb, s, 64);
                if (o > rb) rb = o;
            }
            if (bk == rb && bp >= 0) pool[w * PCAP + bp] = 0ull;  // unique keys
            if (lane == 0) idxbuf[r] = (unsigned)rb;
        }
    }

    // pull the 20 inverted indices into a register before pool is recycled
    const unsigned myidx = idxbuf[(lane < KNN) ? lane : 0];

    __syncthreads();   // all waves done with pools -> safe to reuse as outT

    // ---- epilogue: lane = output channel; neighbors via scalar loads ----
    const int o = lane;
    const float iv   = gamma[o] / sqrtf(var[o] + 1e-5f);
    const float bias = beta[o] - mean[o] * iv;
    const float* Wr = Wm + o * 6;
    const float w0p = Wr[0] * iv, w1p = Wr[1] * iv, w2p = Wr[2] * iv;
    const float w3p = Wr[3] * iv, w4p = Wr[4] * iv, w5p = Wr[5] * iv;
    const float basep = fmaf(w3p, pv.x, fmaf(w4p, pv.y, fmaf(w5p, pv.z, bias)));

    float best = -INFINITY;
    #pragma unroll
    for (int k = 0; k < KNN; ++k) {
        const int lk = __builtin_amdgcn_readlane((int)myidx, k);
        const int gi = __builtin_amdgcn_readfirstlane((NPTS - 1) - lk);
        const float4 f = xqb[gi];                        // uniform -> s_load_dwordx4
        float y = fmaf(w0p, f.x - pv.x,
                   fmaf(w1p, f.y - pv.y,
                    fmaf(w2p, f.z - pv.z, basep)));
        y = fmaxf(y, 0.2f * y);                          // LeakyReLU
        best = fmaxf(best, y);
    }

    float* outT = (float*)pool;                          // 64 x 9 padded
    outT[o * 9 + w] = best;
    __syncthreads();

    // ---- coalesced-ish output: 2 x float4 per channel row ----
    if (t < NOUT * 2) {
        const int oo = t >> 1, seg = t & 1;
        const int sb = oo * 9 + seg * 4;
        float4 vv;
        vv.x = outT[sb + 0]; vv.y = outT[sb + 1];
        vv.z = outT[sb + 2]; vv.w = outT[sb + 3];
        *(float4*)(out + ((size_t)b * NOUT + oo) * NPTS + n0 + seg * 4) = vv;
    }
}

extern "C" void kernel_launch(void* const* d_in, const int* in_sizes, int n_in,
                              void* d_out, int out_size, void* d_ws, size_t ws_size,
                              hipStream_t stream) {
    const float* x     = (const float*)d_in[0];
    const float* Wm    = (const float*)d_in[1];
    const float* gamma = (const float*)d_in[2];
    const float* beta  = (const float*)d_in[3];
    const float* mean  = (const float*)d_in[4];
    const float* var   = (const float*)d_in[5];
    float* out = (float*)d_out;
    float4* xq = (float4*)d_ws;                    // B*NPTS float4 = 512 KB

    const int B = in_sizes[0] / (3 * NPTS);        // 8
    pack_kernel<<<B * NPTS / 256, 256, 0, stream>>>(x, xq);
    const int nblocks = B * (NPTS / QPB);          // 8 * 512 = 4096
    edgeconv_kernel<<<nblocks, BLKT, 0, stream>>>(xq, Wm, gamma, beta, mean, var, out);
}